// Round 6
// baseline (173.056 us; speedup 1.0000x reference)
//
#include <hip/hip_runtime.h>

#define BATCH 100000

typedef float v2 __attribute__((ext_vector_type(2)));

__device__ __forceinline__ v2 fma2(v2 a, v2 b, v2 c) { return __builtin_elementwise_fma(a, b, c); }
__device__ __forceinline__ v2 relu2(v2 a) { v2 z = {0.f, 0.f}; return __builtin_elementwise_max(a, z); }
__device__ __forceinline__ v2 splat(float a) { v2 r = {a, a}; return r; }
__device__ __forceinline__ v2 ldv2(const float* p) { return *(const v2*)p; }
__device__ __forceinline__ float relu(float v) { return fmaxf(v, 0.f); }

// 4 lanes per sample. Lane t: phi neighbors [4t,4t+4), obs [2t,2t+2)
// (linearity: per-lane partial acc, shuffle-summed). rho/psi duplicated
// across the quad (uniform weights -> s_load, zero VMEM in main body).
// launch_bounds(256,8): kernel's natural allocation is 44 VGPR (R5), which
// fits the 64-VGPR/8-waves-per-EU budget -> occupancy cap 100% (was 50%).
// R5 showed ~75% stall on SMEM latency at 2.6 waves/SIMD; this doubles TLP.
// Tripwire: WRITE_SIZE must stay ~781 KB (R3: (256,8) spill showed +25 MB).
__global__ __launch_bounds__(256, 8) void barrier_net(
    const float* __restrict__ x,
    const float* __restrict__ phi_w1, const float* __restrict__ phi_b1,
    const float* __restrict__ phi_w2, const float* __restrict__ phi_b2,
    const float* __restrict__ obs_w1, const float* __restrict__ obs_b1,
    const float* __restrict__ obs_w2, const float* __restrict__ obs_b2,
    const float* __restrict__ rho_w1, const float* __restrict__ rho_b1,
    const float* __restrict__ rho_w2, const float* __restrict__ rho_b2,
    const float* __restrict__ psi_w1, const float* __restrict__ psi_b1,
    const float* __restrict__ psi_w2, const float* __restrict__ psi_b2,
    float2* __restrict__ out)
{
    const int tid = blockIdx.x * 256 + threadIdx.x;
    const int s = tid >> 2;
    const int t = tid & 3;
    if (s >= BATCH) return;
    const float* xr = x + (size_t)s * 85;

    // ---- per-lane slice of the sample ----
    float nb[4][4];                      // my 4 neighbors
    const int nbase = 5 + 16 * t;
#pragma unroll
    for (int n = 0; n < 4; ++n)
#pragma unroll
        for (int k = 0; k < 4; ++k)
            nb[n][k] = xr[nbase + 4 * n + k];

    float ob[2][2];                      // my 2 observations
    const int obase = 69 + 4 * t;
    ob[0][0] = xr[obase];     ob[0][1] = xr[obase + 1];
    ob[1][0] = xr[obase + 2]; ob[1][1] = xr[obase + 3];

    const float g0 = xr[0], g1 = xr[1];

    // ---- barrier partial over my neighbors ----
    float bar0 = 0.f, bar1 = 0.f;
#pragma unroll
    for (int n = 0; n < 4; ++n) {
        float p0 = -nb[n][0], p1 = -nb[n][1];
        float r  = __builtin_amdgcn_sqrtf(fmaf(p0, p0, p1 * p1));
        float sc = 0.01f * __builtin_amdgcn_rcpf(r - 0.2f);
        bar0 = fmaf(sc, p0, bar0);
        bar1 = fmaf(sc, p1, bar1);
    }

    // ---- acc (16 values as 8 float2), per-lane quarter of the bias ----
    v2 acc[8];
#pragma unroll
    for (int p = 0; p < 8; ++p)
        acc[p] = fma2(splat(4.f), ldv2(phi_b2 + 2 * p),
                 fma2(splat(2.f), ldv2(obs_b2 + 2 * p), splat(0.f)));

    // ---- phi: my 4 neighbors, hidden units in pairs ----
#pragma unroll 2
    for (int hp = 0; hp < 32; ++hp) {
        const int h = 2 * hp;
        v2 w0 = ldv2(phi_w1 + h),       w1 = ldv2(phi_w1 + 64 + h);
        v2 w2 = ldv2(phi_w1 + 128 + h), w3 = ldv2(phi_w1 + 192 + h);
        v2 b  = ldv2(phi_b1 + h);
        v2 hs = {0.f, 0.f};
#pragma unroll
        for (int n = 0; n < 4; ++n) {
            v2 tv = fma2(splat(nb[n][0]), w0,
                    fma2(splat(nb[n][1]), w1,
                    fma2(splat(nb[n][2]), w2,
                    fma2(splat(nb[n][3]), w3, b))));
            hs += relu2(tv);
        }
        const float* w2r0 = phi_w2 + (size_t)h * 16;
        v2 hx = splat(hs.x), hy = splat(hs.y);
#pragma unroll
        for (int p = 0; p < 8; ++p)
            acc[p] = fma2(hy, ldv2(w2r0 + 16 + 2 * p),
                     fma2(hx, ldv2(w2r0 + 2 * p), acc[p]));
    }

    // ---- obs: my 2 observations ----
#pragma unroll 2
    for (int hp = 0; hp < 32; ++hp) {
        const int h = 2 * hp;
        v2 w0 = ldv2(obs_w1 + h), w1 = ldv2(obs_w1 + 64 + h);
        v2 b  = ldv2(obs_b1 + h);
        v2 hs = relu2(fma2(splat(ob[0][0]), w0, fma2(splat(ob[0][1]), w1, b)))
              + relu2(fma2(splat(ob[1][0]), w0, fma2(splat(ob[1][1]), w1, b)));
        const float* w2r0 = obs_w2 + (size_t)h * 16;
        v2 hx = splat(hs.x), hy = splat(hs.y);
#pragma unroll
        for (int p = 0; p < 8; ++p)
            acc[p] = fma2(hy, ldv2(w2r0 + 16 + 2 * p),
                     fma2(hx, ldv2(w2r0 + 2 * p), acc[p]));
    }

    // ---- quad tree-sum: acc + barrier ----
#pragma unroll
    for (int p = 0; p < 8; ++p) {
        float a0 = acc[p].x, a1 = acc[p].y;
        a0 += __shfl_xor(a0, 1); a0 += __shfl_xor(a0, 2);
        a1 += __shfl_xor(a1, 1); a1 += __shfl_xor(a1, 2);
        acc[p].x = a0; acc[p].y = a1;
    }
    bar0 += __shfl_xor(bar0, 1); bar0 += __shfl_xor(bar0, 2);
    bar1 += __shfl_xor(bar1, 1); bar1 += __shfl_xor(bar1, 2);

    // ---- rho: 16 -> 64 -> 2, duplicated across quad, uniform weights ----
    v2 rr = ldv2(rho_b2);                // (r0, r1)
#pragma unroll 2
    for (int hp = 0; hp < 32; ++hp) {
        const int h = 2 * hp;
        v2 tt = ldv2(rho_b1 + h);
#pragma unroll
        for (int j = 0; j < 8; ++j) {
            tt = fma2(splat(acc[j].x), ldv2(rho_w1 + (size_t)(2 * j) * 64 + h), tt);
            tt = fma2(splat(acc[j].y), ldv2(rho_w1 + (size_t)(2 * j + 1) * 64 + h), tt);
        }
        tt = relu2(tt);
        rr = fma2(splat(tt.x), ldv2(rho_w2 + 2 * h), rr);
        rr = fma2(splat(tt.y), ldv2(rho_w2 + 2 * h + 2), rr);
    }

    // ---- psi: [r0, r1, g0, g1] -> 64 -> 2, duplicated, uniform weights ----
    v2 ee = ldv2(psi_b2);
#pragma unroll 2
    for (int hp = 0; hp < 32; ++hp) {
        const int h = 2 * hp;
        v2 tt = fma2(splat(rr.x), ldv2(psi_w1 + h),
                fma2(splat(rr.y), ldv2(psi_w1 + 64 + h),
                fma2(splat(g0),   ldv2(psi_w1 + 128 + h),
                fma2(splat(g1),   ldv2(psi_w1 + 192 + h), ldv2(psi_b1 + h)))));
        tt = relu2(tt);
        ee = fma2(splat(tt.x), ldv2(psi_w2 + 2 * h), ee);
        ee = fma2(splat(tt.y), ldv2(psi_w2 + 2 * h + 2), ee);
    }

    if (t == 0) {
        float a0 = tanhf(tanhf(ee.x) + bar0);
        float a1 = tanhf(tanhf(ee.y) + bar1);
        out[s] = make_float2(2.f * a0, 2.f * a1);
    }
}

extern "C" void kernel_launch(void* const* d_in, const int* in_sizes, int n_in,
                              void* d_out, int out_size, void* d_ws, size_t ws_size,
                              hipStream_t stream) {
    const int threads = BATCH * 4;
    dim3 grid((threads + 255) / 256), block(256);
    barrier_net<<<grid, block, 0, stream>>>(
        (const float*)d_in[0],
        (const float*)d_in[1],  (const float*)d_in[2],  (const float*)d_in[3],  (const float*)d_in[4],
        (const float*)d_in[5],  (const float*)d_in[6],  (const float*)d_in[7],  (const float*)d_in[8],
        (const float*)d_in[9],  (const float*)d_in[10], (const float*)d_in[11], (const float*)d_in[12],
        (const float*)d_in[13], (const float*)d_in[14], (const float*)d_in[15], (const float*)d_in[16],
        (float2*)d_out);
}

// Round 7
// 145.868 us; speedup vs baseline: 1.1864x; 1.1864x over previous
//
#include <hip/hip_runtime.h>

#define BATCH 100000

typedef float v2 __attribute__((ext_vector_type(2)));

__device__ __forceinline__ v2 fma2(v2 a, v2 b, v2 c) { return __builtin_elementwise_fma(a, b, c); }
__device__ __forceinline__ v2 relu2(v2 a) { v2 z = {0.f, 0.f}; return __builtin_elementwise_max(a, z); }
__device__ __forceinline__ v2 splat(float a) { v2 r = {a, a}; return r; }
__device__ __forceinline__ v2 ldv2(const float* p) { return *(const v2*)p; }

// 2 lanes per sample. Lane t: phi neighbors [8t,8t+8), obs [4t,4t+4)
// (linearity: per-lane partial acc, one shfl_xor(1) to combine). rho/psi
// duplicated across the pair (uniform weights -> s_load, zero VMEM body).
// Why 2 lanes (R7): quad split (R5) paid 4x duplication on phi-W2/rho/psi
// = 19.4M wave-insts at 24 waves/CU (capped 16); pair split = 11.9M at
// 12.2 waves/CU -> -39% instructions at effectively equal resident TLP,
// with 2x ILP (8 indep neighbor chains) and half the SMEM stream per CU.
// launch_bounds MUST stay (256,4): (256,8) caps VGPR at 32 and spills
// (R3/R6: WRITE_SIZE +25-31 MB tripwire).
__global__ __launch_bounds__(256, 4) void barrier_net(
    const float* __restrict__ x,
    const float* __restrict__ phi_w1, const float* __restrict__ phi_b1,
    const float* __restrict__ phi_w2, const float* __restrict__ phi_b2,
    const float* __restrict__ obs_w1, const float* __restrict__ obs_b1,
    const float* __restrict__ obs_w2, const float* __restrict__ obs_b2,
    const float* __restrict__ rho_w1, const float* __restrict__ rho_b1,
    const float* __restrict__ rho_w2, const float* __restrict__ rho_b2,
    const float* __restrict__ psi_w1, const float* __restrict__ psi_b1,
    const float* __restrict__ psi_w2, const float* __restrict__ psi_b2,
    float2* __restrict__ out)
{
    const int tid = blockIdx.x * 256 + threadIdx.x;
    const int s = tid >> 1;
    const int t = tid & 1;
    if (s >= BATCH) return;
    const float* xr = x + (size_t)s * 85;

    // ---- per-lane slice: 8 neighbors, 4 observations ----
    float nb[8][4];
    const int nbase = 5 + 32 * t;
#pragma unroll
    for (int n = 0; n < 8; ++n)
#pragma unroll
        for (int k = 0; k < 4; ++k)
            nb[n][k] = xr[nbase + 4 * n + k];

    float ob[4][2];
    const int obase = 69 + 8 * t;
#pragma unroll
    for (int o = 0; o < 4; ++o) {
        ob[o][0] = xr[obase + 2 * o];
        ob[o][1] = xr[obase + 2 * o + 1];
    }

    const float g0 = xr[0], g1 = xr[1];

    // ---- barrier partial over my 8 neighbors ----
    float bar0 = 0.f, bar1 = 0.f;
#pragma unroll
    for (int n = 0; n < 8; ++n) {
        float p0 = -nb[n][0], p1 = -nb[n][1];
        float r  = __builtin_amdgcn_sqrtf(fmaf(p0, p0, p1 * p1));
        float sc = 0.01f * __builtin_amdgcn_rcpf(r - 0.2f);
        bar0 = fmaf(sc, p0, bar0);
        bar1 = fmaf(sc, p1, bar1);
    }

    // ---- acc partial (16 values as 8 float2): each lane half the bias ----
    v2 acc[8];
#pragma unroll
    for (int p = 0; p < 8; ++p)
        acc[p] = fma2(splat(8.f), ldv2(phi_b2 + 2 * p),
                 fma2(splat(4.f), ldv2(obs_b2 + 2 * p), splat(0.f)));

    // ---- phi: my 8 neighbors, hidden units in pairs ----
#pragma unroll 2
    for (int hp = 0; hp < 32; ++hp) {
        const int h = 2 * hp;
        v2 w0 = ldv2(phi_w1 + h),       w1 = ldv2(phi_w1 + 64 + h);
        v2 w2 = ldv2(phi_w1 + 128 + h), w3 = ldv2(phi_w1 + 192 + h);
        v2 b  = ldv2(phi_b1 + h);
        v2 hs = {0.f, 0.f};
#pragma unroll
        for (int n = 0; n < 8; ++n) {
            v2 tv = fma2(splat(nb[n][0]), w0,
                    fma2(splat(nb[n][1]), w1,
                    fma2(splat(nb[n][2]), w2,
                    fma2(splat(nb[n][3]), w3, b))));
            hs += relu2(tv);
        }
        const float* w2r0 = phi_w2 + (size_t)h * 16;
        v2 hx = splat(hs.x), hy = splat(hs.y);
#pragma unroll
        for (int p = 0; p < 8; ++p)
            acc[p] = fma2(hy, ldv2(w2r0 + 16 + 2 * p),
                     fma2(hx, ldv2(w2r0 + 2 * p), acc[p]));
    }

    // ---- obs: my 4 observations ----
#pragma unroll 2
    for (int hp = 0; hp < 32; ++hp) {
        const int h = 2 * hp;
        v2 w0 = ldv2(obs_w1 + h), w1 = ldv2(obs_w1 + 64 + h);
        v2 b  = ldv2(obs_b1 + h);
        v2 hs = {0.f, 0.f};
#pragma unroll
        for (int o = 0; o < 4; ++o)
            hs += relu2(fma2(splat(ob[o][0]), w0, fma2(splat(ob[o][1]), w1, b)));
        const float* w2r0 = obs_w2 + (size_t)h * 16;
        v2 hx = splat(hs.x), hy = splat(hs.y);
#pragma unroll
        for (int p = 0; p < 8; ++p)
            acc[p] = fma2(hy, ldv2(w2r0 + 16 + 2 * p),
                     fma2(hx, ldv2(w2r0 + 2 * p), acc[p]));
    }

    // ---- pair tree-sum: acc + barrier (one xor step) ----
#pragma unroll
    for (int p = 0; p < 8; ++p) {
        acc[p].x += __shfl_xor(acc[p].x, 1);
        acc[p].y += __shfl_xor(acc[p].y, 1);
    }
    bar0 += __shfl_xor(bar0, 1);
    bar1 += __shfl_xor(bar1, 1);

    // ---- rho: 16 -> 64 -> 2, duplicated across pair, uniform weights ----
    v2 rr = ldv2(rho_b2);                // (r0, r1)
#pragma unroll 2
    for (int hp = 0; hp < 32; ++hp) {
        const int h = 2 * hp;
        v2 tt = ldv2(rho_b1 + h);
#pragma unroll
        for (int j = 0; j < 8; ++j) {
            tt = fma2(splat(acc[j].x), ldv2(rho_w1 + (size_t)(2 * j) * 64 + h), tt);
            tt = fma2(splat(acc[j].y), ldv2(rho_w1 + (size_t)(2 * j + 1) * 64 + h), tt);
        }
        tt = relu2(tt);
        rr = fma2(splat(tt.x), ldv2(rho_w2 + 2 * h), rr);
        rr = fma2(splat(tt.y), ldv2(rho_w2 + 2 * h + 2), rr);
    }

    // ---- psi: [r0, r1, g0, g1] -> 64 -> 2, duplicated, uniform weights ----
    v2 ee = ldv2(psi_b2);
#pragma unroll 2
    for (int hp = 0; hp < 32; ++hp) {
        const int h = 2 * hp;
        v2 tt = fma2(splat(rr.x), ldv2(psi_w1 + h),
                fma2(splat(rr.y), ldv2(psi_w1 + 64 + h),
                fma2(splat(g0),   ldv2(psi_w1 + 128 + h),
                fma2(splat(g1),   ldv2(psi_w1 + 192 + h), ldv2(psi_b1 + h)))));
        tt = relu2(tt);
        ee = fma2(splat(tt.x), ldv2(psi_w2 + 2 * h), ee);
        ee = fma2(splat(tt.y), ldv2(psi_w2 + 2 * h + 2), ee);
    }

    if (t == 0) {
        float a0 = tanhf(tanhf(ee.x) + bar0);
        float a1 = tanhf(tanhf(ee.y) + bar1);
        out[s] = make_float2(2.f * a0, 2.f * a1);
    }
}

extern "C" void kernel_launch(void* const* d_in, const int* in_sizes, int n_in,
                              void* d_out, int out_size, void* d_ws, size_t ws_size,
                              hipStream_t stream) {
    const int threads = BATCH * 2;
    dim3 grid((threads + 255) / 256), block(256);
    barrier_net<<<grid, block, 0, stream>>>(
        (const float*)d_in[0],
        (const float*)d_in[1],  (const float*)d_in[2],  (const float*)d_in[3],  (const float*)d_in[4],
        (const float*)d_in[5],  (const float*)d_in[6],  (const float*)d_in[7],  (const float*)d_in[8],
        (const float*)d_in[9],  (const float*)d_in[10], (const float*)d_in[11], (const float*)d_in[12],
        (const float*)d_in[13], (const float*)d_in[14], (const float*)d_in[15], (const float*)d_in[16],
        (float2*)d_out);
}

// Round 8
// 145.395 us; speedup vs baseline: 1.1902x; 1.0033x over previous
//
#include <hip/hip_runtime.h>

#define BATCH 100000

typedef float v2 __attribute__((ext_vector_type(2)));

__device__ __forceinline__ v2 fma2(v2 a, v2 b, v2 c) { return __builtin_elementwise_fma(a, b, c); }
__device__ __forceinline__ v2 relu2(v2 a) { v2 z = {0.f, 0.f}; return __builtin_elementwise_max(a, z); }
__device__ __forceinline__ v2 splat(float a) { v2 r = {a, a}; return r; }
__device__ __forceinline__ v2 ldv2(const float* p) { return *(const v2*)p; }

// 2 lanes per sample; lane t: phi neighbors [8t,8t+8), obs [4t,4t+4)
// (linearity: partial acc per lane, one shfl_xor to combine); rho/psi
// duplicated across the pair (weights stay wave-uniform -> s_load only,
// zero VMEM in the main body).
// R8: hidden dim processed in chunks of 8 (4 x v2), rows OUTER / chunk
// INNER, so every weight read is a contiguous 8-16 dword segment ->
// s_load_dwordx8/x16 bursts instead of R7's ~1200 strided dwordx2
// (R7 was 59% SMEM-latency stalled; ALU cycles are unchanged).
// launch_bounds MUST stay (256,4): (256,8) caps VGPR at 32 and spills
// (R3/R6 tripwire: WRITE_SIZE +25-31 MB). v_pk_fma_f32 is issue-slot
// savings only (f32 pipe is 2 FLOP/lane/cyc total; 157.3 TF spec).
__global__ __launch_bounds__(256, 4) void barrier_net(
    const float* __restrict__ x,
    const float* __restrict__ phi_w1, const float* __restrict__ phi_b1,
    const float* __restrict__ phi_w2, const float* __restrict__ phi_b2,
    const float* __restrict__ obs_w1, const float* __restrict__ obs_b1,
    const float* __restrict__ obs_w2, const float* __restrict__ obs_b2,
    const float* __restrict__ rho_w1, const float* __restrict__ rho_b1,
    const float* __restrict__ rho_w2, const float* __restrict__ rho_b2,
    const float* __restrict__ psi_w1, const float* __restrict__ psi_b1,
    const float* __restrict__ psi_w2, const float* __restrict__ psi_b2,
    float2* __restrict__ out)
{
    const int tid = blockIdx.x * 256 + threadIdx.x;
    const int s = tid >> 1;
    const int t = tid & 1;
    if (s >= BATCH) return;
    const float* xr = x + (size_t)s * 85;

    // ---- per-lane slice: 8 neighbors, 4 observations ----
    float nb[8][4];
    const int nbase = 5 + 32 * t;
#pragma unroll
    for (int n = 0; n < 8; ++n)
#pragma unroll
        for (int k = 0; k < 4; ++k)
            nb[n][k] = xr[nbase + 4 * n + k];

    float ob[4][2];
    const int obase = 69 + 8 * t;
#pragma unroll
    for (int o = 0; o < 4; ++o) {
        ob[o][0] = xr[obase + 2 * o];
        ob[o][1] = xr[obase + 2 * o + 1];
    }

    const float g0 = xr[0], g1 = xr[1];

    // ---- barrier partial over my 8 neighbors ----
    float bar0 = 0.f, bar1 = 0.f;
#pragma unroll
    for (int n = 0; n < 8; ++n) {
        float p0 = -nb[n][0], p1 = -nb[n][1];
        float r  = __builtin_amdgcn_sqrtf(fmaf(p0, p0, p1 * p1));
        float sc = 0.01f * __builtin_amdgcn_rcpf(r - 0.2f);
        bar0 = fmaf(sc, p0, bar0);
        bar1 = fmaf(sc, p1, bar1);
    }

    // ---- acc partial (16 as 8 v2): each lane carries half the bias ----
    v2 acc[8];
#pragma unroll
    for (int p = 0; p < 8; ++p)
        acc[p] = fma2(splat(8.f), ldv2(phi_b2 + 2 * p),
                 fma2(splat(4.f), ldv2(obs_b2 + 2 * p), splat(0.f)));

    // ---- phi: chunks of 8 h; w1 row-segments + W2 rows all contiguous ----
#pragma unroll 2
    for (int c = 0; c < 8; ++c) {
        const int hb = c * 8;
        v2 hsv[4] = {{0.f,0.f},{0.f,0.f},{0.f,0.f},{0.f,0.f}};
#pragma unroll
        for (int n = 0; n < 8; ++n) {
#pragma unroll
            for (int p = 0; p < 4; ++p) {
                v2 tv = fma2(splat(nb[n][0]), ldv2(phi_w1 + hb + 2 * p),
                        fma2(splat(nb[n][1]), ldv2(phi_w1 + 64 + hb + 2 * p),
                        fma2(splat(nb[n][2]), ldv2(phi_w1 + 128 + hb + 2 * p),
                        fma2(splat(nb[n][3]), ldv2(phi_w1 + 192 + hb + 2 * p),
                                              ldv2(phi_b1 + hb + 2 * p)))));
                hsv[p] += relu2(tv);
            }
        }
#pragma unroll
        for (int p = 0; p < 4; ++p) {
            const float* r0 = phi_w2 + (size_t)(hb + 2 * p) * 16;
            v2 hx = splat(hsv[p].x), hy = splat(hsv[p].y);
#pragma unroll
            for (int q = 0; q < 8; ++q)
                acc[q] = fma2(hy, ldv2(r0 + 16 + 2 * q),
                         fma2(hx, ldv2(r0 + 2 * q), acc[q]));
        }
    }

    // ---- obs: same chunking ----
#pragma unroll 2
    for (int c = 0; c < 8; ++c) {
        const int hb = c * 8;
        v2 hsv[4] = {{0.f,0.f},{0.f,0.f},{0.f,0.f},{0.f,0.f}};
#pragma unroll
        for (int o = 0; o < 4; ++o) {
#pragma unroll
            for (int p = 0; p < 4; ++p) {
                v2 tv = fma2(splat(ob[o][0]), ldv2(obs_w1 + hb + 2 * p),
                        fma2(splat(ob[o][1]), ldv2(obs_w1 + 64 + hb + 2 * p),
                                              ldv2(obs_b1 + hb + 2 * p)));
                hsv[p] += relu2(tv);
            }
        }
#pragma unroll
        for (int p = 0; p < 4; ++p) {
            const float* r0 = obs_w2 + (size_t)(hb + 2 * p) * 16;
            v2 hx = splat(hsv[p].x), hy = splat(hsv[p].y);
#pragma unroll
            for (int q = 0; q < 8; ++q)
                acc[q] = fma2(hy, ldv2(r0 + 16 + 2 * q),
                         fma2(hx, ldv2(r0 + 2 * q), acc[q]));
        }
    }

    // ---- pair-sum: acc + barrier ----
#pragma unroll
    for (int p = 0; p < 8; ++p) {
        acc[p].x += __shfl_xor(acc[p].x, 1);
        acc[p].y += __shfl_xor(acc[p].y, 1);
    }
    bar0 += __shfl_xor(bar0, 1);
    bar1 += __shfl_xor(bar1, 1);

    // ---- rho: 16 -> 64 -> 2, duplicated, chunked (row-segment reads) ----
    v2 rr = ldv2(rho_b2);
#pragma unroll 2
    for (int c = 0; c < 8; ++c) {
        const int hb = c * 8;
        v2 tt[4];
#pragma unroll
        for (int p = 0; p < 4; ++p)
            tt[p] = ldv2(rho_b1 + hb + 2 * p);
#pragma unroll
        for (int j = 0; j < 8; ++j) {
            v2 ax = splat(acc[j].x), ay = splat(acc[j].y);
            const float* rj0 = rho_w1 + (size_t)(2 * j) * 64 + hb;
            const float* rj1 = rho_w1 + (size_t)(2 * j + 1) * 64 + hb;
#pragma unroll
            for (int p = 0; p < 4; ++p)
                tt[p] = fma2(ay, ldv2(rj1 + 2 * p),
                        fma2(ax, ldv2(rj0 + 2 * p), tt[p]));
        }
#pragma unroll
        for (int p = 0; p < 4; ++p) {
            v2 u = relu2(tt[p]);
            rr = fma2(splat(u.x), ldv2(rho_w2 + 2 * (hb + 2 * p)), rr);
            rr = fma2(splat(u.y), ldv2(rho_w2 + 2 * (hb + 2 * p) + 2), rr);
        }
    }

    // ---- psi: [r0, r1, g0, g1] -> 64 -> 2, duplicated, chunked ----
    v2 ee = ldv2(psi_b2);
#pragma unroll 2
    for (int c = 0; c < 8; ++c) {
        const int hb = c * 8;
#pragma unroll
        for (int p = 0; p < 4; ++p) {
            v2 tv = fma2(splat(rr.x), ldv2(psi_w1 + hb + 2 * p),
                    fma2(splat(rr.y), ldv2(psi_w1 + 64 + hb + 2 * p),
                    fma2(splat(g0),   ldv2(psi_w1 + 128 + hb + 2 * p),
                    fma2(splat(g1),   ldv2(psi_w1 + 192 + hb + 2 * p),
                                      ldv2(psi_b1 + hb + 2 * p)))));
            v2 u = relu2(tv);
            ee = fma2(splat(u.x), ldv2(psi_w2 + 2 * (hb + 2 * p)), ee);
            ee = fma2(splat(u.y), ldv2(psi_w2 + 2 * (hb + 2 * p) + 2), ee);
        }
    }

    if (t == 0) {
        float a0 = tanhf(tanhf(ee.x) + bar0);
        float a1 = tanhf(tanhf(ee.y) + bar1);
        out[s] = make_float2(2.f * a0, 2.f * a1);
    }
}

extern "C" void kernel_launch(void* const* d_in, const int* in_sizes, int n_in,
                              void* d_out, int out_size, void* d_ws, size_t ws_size,
                              hipStream_t stream) {
    const int threads = BATCH * 2;
    dim3 grid((threads + 255) / 256), block(256);
    barrier_net<<<grid, block, 0, stream>>>(
        (const float*)d_in[0],
        (const float*)d_in[1],  (const float*)d_in[2],  (const float*)d_in[3],  (const float*)d_in[4],
        (const float*)d_in[5],  (const float*)d_in[6],  (const float*)d_in[7],  (const float*)d_in[8],
        (const float*)d_in[9],  (const float*)d_in[10], (const float*)d_in[11], (const float*)d_in[12],
        (const float*)d_in[13], (const float*)d_in[14], (const float*)d_in[15], (const float*)d_in[16],
        (float2*)d_out);
}